// Round 3
// baseline (344.111 us; speedup 1.0000x reference)
//
#include <hip/hip_runtime.h>
#include <math.h>

#define E_TOT   10240
#define N_NODES 512
#define NCOL    11520

typedef unsigned short ushort_t;
typedef unsigned int   uint_t;
typedef __bf16 bf16x8 __attribute__((ext_vector_type(8)));
typedef float  f32x4  __attribute__((ext_vector_type(4)));

constexpr float EPSF        = 1e-5f;
constexpr float INV_SQRT128 = 0.08838834764831845f;
constexpr float INV_SQRT112 = 0.09449111825230681f;
constexpr float INV_SQRT48  = 0.14433756729740643f;
constexpr float INV_SQRT32  = 0.17677669529663687f;
constexpr float INV_SQRT16  = 0.25f;
constexpr float INV_SQRT8   = 0.35355339059327373f;
constexpr float SC0 = INV_SQRT128 * INV_SQRT112;
constexpr float SC1 = INV_SQRT128 * INV_SQRT48;
constexpr float SC2 = INV_SQRT128 * INV_SQRT16;
constexpr float C_OLD_ = 0.8944271909999159f;
constexpr float C_NEW_ = 0.4472135954999579f;
constexpr float NORMC  = 0.22360679774997896f;

// ---------------------------------------------------------------- utilities
__device__ __forceinline__ float wsum(float v) {
#pragma unroll
  for (int off = 32; off > 0; off >>= 1) v += __shfl_xor(v, off, 64);
  return v;
}

__device__ __forceinline__ ushort_t f2bf(float x) {
  uint_t u = __float_as_uint(x);
  u = (u + 0x7fffu + ((u >> 16) & 1u)) >> 16;
  return (ushort_t)u;
}

// Analytic Wigner-D (l=2) in basis {xy, yz, 3z^2-1, xz, x^2-y^2}.
__device__ __forceinline__ void wigner5(const float q[9], float D[25]) {
  const float q0x=q[0],q0y=q[1],q0z=q[2];
  const float q1x=q[3],q1y=q[4],q1z=q[5];
  const float q2x=q[6],q2y=q[7],q2z=q[8];
  D[0]  = q0x*q1y + q1x*q0y;
  D[1]  = q0y*q1z + q1y*q0z;
  D[2]  = 0.5f*(q0z*q1z);
  D[3]  = q0x*q1z + q1x*q0z;
  D[4]  = 0.5f*(q0x*q1x - q0y*q1y);
  D[5]  = q1x*q2y + q2x*q1y;
  D[6]  = q1y*q2z + q2y*q1z;
  D[7]  = 0.5f*(q1z*q2z);
  D[8]  = q1x*q2z + q2x*q1z;
  D[9]  = 0.5f*(q1x*q2x - q1y*q2y);
  D[10] = 6.f*q2x*q2y;
  D[11] = 6.f*q2y*q2z;
  D[12] = 0.5f*(3.f*q2z*q2z - 1.f);
  D[13] = 6.f*q2x*q2z;
  D[14] = 1.5f*(q2x*q2x - q2y*q2y);
  D[15] = q0x*q2y + q2x*q0y;
  D[16] = q0y*q2z + q2y*q0z;
  D[17] = 0.5f*(q0z*q2z);
  D[18] = q0x*q2z + q2x*q0z;
  D[19] = 0.5f*(q0x*q2x - q0y*q2y);
  D[20] = 2.f*(q0x*q0y - q1x*q1y);
  D[21] = 2.f*(q0y*q0z - q1y*q1z);
  D[22] = 0.5f*(q0z*q0z - q1z*q1z);
  D[23] = 2.f*(q0x*q0z - q1x*q1z);
  D[24] = 0.5f*((q0x*q0x - q1x*q1x) - (q0y*q0y - q1y*q1y));
}

// ---------------------------------------------------------------- K0: latents -> bf16 hi/lo
__global__ void k0_latpack(const float* __restrict__ lat,
                           ushort_t* __restrict__ lath, ushort_t* __restrict__ latl) {
  int idx = blockIdx.x*256 + threadIdx.x;
  if (idx >= E_TOT*128) return;
  float x = lat[idx];
  ushort_t h = f2bf(x);
  float hf = __uint_as_float(((uint_t)h) << 16);
  lath[idx] = h;
  latl[idx] = f2bf(x - hf);
}

// -------------------------------------- K_pack: W_tp -> contiguous-c MFMA fragments
// Column table (720 tiles total):
//  col0-4 : sec0   o-block a=col, depth 112, c = t*80 + 16a + m
//  col5   : w1r oA, depth 48, c = 8960 + t*24 + m
//  col6   : w1r oB, depth 24, c = 8960 + (2t+(m>>3))*24 + 16 + (m&7)
//  col7   : w1i oA, depth 48, c = 10112 + t*24 + m
//  col8   : w1i oB, depth 24, c = 10112 + (2t+(m>>3))*24 + 16 + (m&7)
//  col9   : w2r,    depth 8,  c = 11264 + (2t+(m>>3))*8 + (m&7)
//  col10  : w2i,    depth 8,  c = 11392 + (2t+(m>>3))*8 + (m&7)
// Fragment layout: frag(nt,kc,s)[lane][8] at ((nt*8 + kc*2 + s)*512 + lane*8)
__global__ void k_pack(const float* __restrict__ Wtp, ushort_t* __restrict__ Wp) {
  const int nt = blockIdx.x;
  const int t = threadIdx.x;
  const int kc = t >> 6, lane = t & 63;
  const int m = lane & 15, kg = lane >> 4;
  int col, tt;
  if (nt < 560)      { col = nt/112; tt = nt - col*112; }
  else if (nt < 608) { col = 5;  tt = nt-560; }
  else if (nt < 632) { col = 6;  tt = nt-608; }
  else if (nt < 680) { col = 7;  tt = nt-632; }
  else if (nt < 704) { col = 8;  tt = nt-680; }
  else if (nt < 712) { col = 9;  tt = nt-704; }
  else               { col = 10; tt = nt-712; }
  int c; float sc;
  switch (col) {
    case 5:  c = 8960  + tt*24 + m;                      sc = SC1; break;
    case 6:  c = 8960  + (2*tt + (m>>3))*24 + 16 + (m&7); sc = SC1; break;
    case 7:  c = 10112 + tt*24 + m;                      sc = SC1; break;
    case 8:  c = 10112 + (2*tt + (m>>3))*24 + 16 + (m&7); sc = SC1; break;
    case 9:  c = 11264 + (2*tt + (m>>3))*8 + (m&7);      sc = SC2; break;
    case 10: c = 11392 + (2*tt + (m>>3))*8 + (m&7);      sc = SC2; break;
    default: c = tt*80 + col*16 + m;                     sc = SC0; break;
  }
  ushort_t hi[8], lo[8];
#pragma unroll
  for (int jj = 0; jj < 8; ++jj) {
    int l = kc*32 + kg*8 + jj;
    float w = Wtp[(size_t)l*NCOL + c] * sc;
    ushort_t h = f2bf(w);
    float hf = __uint_as_float(((uint_t)h) << 16);
    hi[jj] = h;
    lo[jj] = f2bf(w - hf);
  }
  size_t base = ((size_t)nt*8 + kc*2)*512 + (size_t)lane*8;
#pragma unroll
  for (int jj = 0; jj < 8; ++jj) {
    Wp[base + jj]       = hi[jj];
    Wp[base + 512 + jj] = lo[jj];
  }
}

// ---------------------------------------------------------------- K1: _sln
__global__ void k1_sln(const float* __restrict__ x_all,
                       const float* __restrict__ w0, const float* __restrict__ b0,
                       const float* __restrict__ w1, const float* __restrict__ w2,
                       float* __restrict__ nf) {
  const int n = blockIdx.x;
  const int t = threadIdx.x;
  const float* x = x_all + n*120;
  float xs = (t < 32) ? x[t] : 0.f;
  float ssum = wsum(xs);
  float ssq  = wsum(xs*xs);
  float mu   = ssum * (1.f/32.f);
  float var  = ssq * (1.f/32.f) - mu*mu;
  float istd = rsqrtf(var + EPSF);
  float q1 = (t < 48) ? x[32+t] : 0.f;
  float v1s = wsum(q1*q1);
  float q2 = (t < 40) ? x[80+t] : 0.f;
  float v2s = wsum(q2*q2);
  float inv = rsqrtf(0.5f*(v1s*(1.f/48.f) + v2s*(1.f/40.f)) + EPSF);
  for (int j = t; j < 120; j += 64) {
    float val = x[j], r;
    if (j < 32)      r = (val - mu)*istd*w0[j] + b0[j];
    else if (j < 80) r = val*inv*w1[(j-32)/3];
    else             r = val*inv*w2[(j-80)/5];
    nf[n*120 + j] = r;
  }
}

// ------------------------------------------------- K2: per-edge preprocessing
// invT layout: [r][E_TOT]  (r = 0..239), coalesced stores across lanes.
// rows: in0 @0 (112) | inn1 @112 (48) | inp1 @160 (48) | inn2 @208 (16) | inp2 @224 (16)
__global__ void k2_edge_prep(const float* __restrict__ hid,
                             const float* __restrict__ evec,
                             const int*   __restrict__ eidx,
                             const int*   __restrict__ act,
                             const float* __restrict__ nf,
                             float* __restrict__ invT,
                             float* __restrict__ Rm,
                             float* __restrict__ D2bm) {
  const int e = blockIdx.x*blockDim.x + threadIdx.x;
  if (e >= E_TOT) return;
  const int ae  = act[e];
  const int ctr = eidx[ae];
  float vx = evec[ae*3+0], vy = evec[ae*3+1], vz = evec[ae*3+2];
  float rn = rsqrtf(vx*vx + vy*vy + vz*vz);
  float nx = vx*rn, ny = vy*rn, nz = vz*rn;
  float e1x, e1y, e1z;
  if (fabsf(nz) < 0.99f) { e1x = -ny; e1y = nx;  e1z = 0.f; }
  else                   { e1x = 0.f; e1y = -nz; e1z = ny;  }
  float rl = rsqrtf(e1x*e1x + e1y*e1y + e1z*e1z);
  e1x *= rl; e1y *= rl; e1z *= rl;
  float e2x = ny*e1z - nz*e1y;
  float e2y = nz*e1x - nx*e1z;
  float e2z = nx*e1y - ny*e1x;
  float R[9] = {e1x,e1y,e1z, e2x,e2y,e2z, nx,ny,nz};
#pragma unroll
  for (int j = 0; j < 9; ++j) Rm[e*9 + j] = R[j];
  float Df[25];
  wigner5(R, Df);
  float Rt[9] = {R[0],R[3],R[6], R[1],R[4],R[7], R[2],R[5],R[8]};
  float Db[25];
  wigner5(Rt, Db);
#pragma unroll
  for (int j = 0; j < 25; ++j) D2bm[e*25 + j] = Db[j];
  const float* xa = nf  + (size_t)ctr*120;
  const float* xb = hid + (size_t)e*120;
#define IVST(r_, v_) invT[(size_t)(r_)*E_TOT + e] = (v_)
#pragma unroll
  for (int j = 0; j < 32; ++j) { IVST(j, xa[j]); IVST(32+j, xb[j]); }
#pragma unroll
  for (int u = 0; u < 32; ++u) {
    const float* src = (u < 16) ? (xa + 32 + 3*u) : (xb + 32 + 3*(u-16));
    float px = src[0], py = src[1], pz = src[2];
    float rx = R[0]*px + R[1]*py + R[2]*pz;
    float ry = R[3]*px + R[4]*py + R[5]*pz;
    float rz = R[6]*px + R[7]*py + R[8]*pz;
    IVST(64+u, ry);
    IVST(112+u, rx);
    IVST(160+u, rz);
  }
#pragma unroll
  for (int u = 0; u < 16; ++u) {
    const float* src = (u < 8) ? (xa + 80 + 5*u) : (xb + 80 + 5*(u-8));
    float p0 = src[0], p1 = src[1], p2 = src[2], p3 = src[3], p4 = src[4];
    float d[5];
#pragma unroll
    for (int i = 0; i < 5; ++i)
      d[i] = Df[i*5+0]*p0 + Df[i*5+1]*p1 + Df[i*5+2]*p2 + Df[i*5+3]*p3 + Df[i*5+4]*p4;
    IVST(96+u,  d[2]);
    IVST(144+u, d[1]);
    IVST(192+u, d[3]);
    IVST(208+u, d[0]);
    IVST(224+u, d[4]);
  }
#undef IVST
}

// ------------------------------------------------- K2w: wenv
__global__ void k2_wenv(const float* __restrict__ lat, const float* __restrict__ Wenv,
                        const int* __restrict__ act, float* __restrict__ wenvo) {
  const int e = blockIdx.x*4 + (threadIdx.x >> 6);
  const int o = threadIdx.x & 63;
  if (o >= 56) return;
  const int ae = act[e];
  const float* lrow = lat + (size_t)ae*128;
  float s = 0.f;
  for (int l = 0; l < 128; ++l) s += lrow[l]*Wenv[l*56 + o];
  wenvo[(size_t)e*56 + o] = s * INV_SQRT128;
}

// --------------------------- K3: MFMA GEMM, contiguous-c tiles, register accumulation
template<bool TWO, bool PAIR>
__device__ __forceinline__ void run_seg(
    const bf16x8* __restrict__ W8, int f0, int f1, int tstart,
    int multP, int multN, int slotP, int slotN, float sgnP,
    const float* __restrict__ in_lds,
    const bf16x8 (&Bh)[4][2], const bf16x8 (&Bl)[4][2],
    int lane, int e0, float* __restrict__ oa) {
  const int le = lane & 15, g = lane >> 4, gh = g >> 1;
  f32x4 aP0 = {0,0,0,0}, aP1 = {0,0,0,0}, aN0 = {0,0,0,0}, aN1 = {0,0,0,0};
  for (int f = f0; f < f1; ++f) {
    const bf16x8* ap = W8 + (size_t)f*512 + lane;
    f32x4 d0 = {0,0,0,0}, d1 = {0,0,0,0};
#pragma unroll
    for (int kc = 0; kc < 4; ++kc) {
      bf16x8 Ah = ap[(kc*2+0)*64];
      bf16x8 Al = ap[(kc*2+1)*64];
      d0 = __builtin_amdgcn_mfma_f32_16x16x32_bf16(Ah, Bh[kc][0], d0, 0, 0, 0);
      d1 = __builtin_amdgcn_mfma_f32_16x16x32_bf16(Ah, Bh[kc][1], d1, 0, 0, 0);
      d0 = __builtin_amdgcn_mfma_f32_16x16x32_bf16(Ah, Bl[kc][0], d0, 0, 0, 0);
      d1 = __builtin_amdgcn_mfma_f32_16x16x32_bf16(Ah, Bl[kc][1], d1, 0, 0, 0);
      d0 = __builtin_amdgcn_mfma_f32_16x16x32_bf16(Al, Bh[kc][0], d0, 0, 0, 0);
      d1 = __builtin_amdgcn_mfma_f32_16x16x32_bf16(Al, Bh[kc][1], d1, 0, 0, 0);
    }
    int tt = f - tstart;
    int idx = PAIR ? (2*tt + gh) : tt;
    float mP0 = in_lds[(multP+idx)*32 + le];
    float mP1 = in_lds[(multP+idx)*32 + 16 + le];
#pragma unroll
    for (int r = 0; r < 4; ++r) { aP0[r] += mP0*d0[r]; aP1[r] += mP1*d1[r]; }
    if (TWO) {
      float mN0 = in_lds[(multN+idx)*32 + le];
      float mN1 = in_lds[(multN+idx)*32 + 16 + le];
#pragma unroll
      for (int r = 0; r < 4; ++r) { aN0[r] += mN0*d0[r]; aN1[r] += mN1*d1[r]; }
    }
  }
#pragma unroll
  for (int r = 0; r < 4; ++r) {
    int mm = g*4 + r;
    int sp = slotP + (PAIR ? (mm & 7) : mm);
    atomicAdd(&oa[(size_t)e0*144 + sp], sgnP*aP0[r]);
    atomicAdd(&oa[(size_t)(e0+16)*144 + sp], sgnP*aP1[r]);
    if (TWO) {
      int sn = slotN + (PAIR ? (mm & 7) : mm);
      atomicAdd(&oa[(size_t)e0*144 + sn], aN0[r]);
      atomicAdd(&oa[(size_t)(e0+16)*144 + sn], aN1[r]);
    }
  }
}

__global__ __launch_bounds__(256, 4)
void k3_gemm(const ushort_t* __restrict__ Wp,
             const ushort_t* __restrict__ lath,
             const ushort_t* __restrict__ latl,
             const float*  __restrict__ invT,
             float* __restrict__ oa_g) {
  __shared__ float in_lds[240*32];
  const int t = threadIdx.x;
  const int eb = blockIdx.x;
  for (int i = t; i < 240*32; i += 256) {
    int r = i >> 5, e = i & 31;
    in_lds[i] = invT[(size_t)r*E_TOT + eb*32 + e];
  }
  const int wave = t >> 6, lane = t & 63;
  const int le = lane & 15, g = lane >> 4;
  bf16x8 Bh[4][2], Bl[4][2];
  {
    const int e0 = eb*32 + le;
    const int ko = g*8;
#pragma unroll
    for (int kc = 0; kc < 4; ++kc) {
#pragma unroll
      for (int n = 0; n < 2; ++n) {
        size_t off = (size_t)(e0 + 16*n)*128 + kc*32 + ko;
        Bh[kc][n] = *(const bf16x8*)(lath + off);
        Bl[kc][n] = *(const bf16x8*)(latl + off);
      }
    }
  }
  __syncthreads();
  const bf16x8* W8 = (const bf16x8*)Wp;
  const int e0 = eb*32 + le;
  const int f0 = (blockIdx.y*4 + wave)*45, f1 = f0 + 45;
  int lo, hi;
  // cols 0-4 (sec0)
#pragma unroll
  for (int col = 0; col < 5; ++col) {
    int s = col*112, epos = s + 112;
    lo = f0 > s ? f0 : s; hi = f1 < epos ? f1 : epos;
    if (lo < hi)
      run_seg<false,false>(W8, lo, hi, s, 0, 0, col*16, 0, 1.f,
                           in_lds, Bh, Bl, lane, e0, oa_g);
  }
  // col5: w1r oA [560,608)
  lo = f0 > 560 ? f0 : 560; hi = f1 < 608 ? f1 : 608;
  if (lo < hi) run_seg<true,false>(W8, lo, hi, 560, 160, 112, 80, 104, 1.f,
                                   in_lds, Bh, Bl, lane, e0, oa_g);
  // col6: w1r oB [608,632)
  lo = f0 > 608 ? f0 : 608; hi = f1 < 632 ? f1 : 632;
  if (lo < hi) run_seg<true,true>(W8, lo, hi, 608, 160, 112, 96, 120, 1.f,
                                  in_lds, Bh, Bl, lane, e0, oa_g);
  // col7: w1i oA [632,680)
  lo = f0 > 632 ? f0 : 632; hi = f1 < 680 ? f1 : 680;
  if (lo < hi) run_seg<true,false>(W8, lo, hi, 632, 112, 160, 80, 104, -1.f,
                                   in_lds, Bh, Bl, lane, e0, oa_g);
  // col8: w1i oB [680,704)
  lo = f0 > 680 ? f0 : 680; hi = f1 < 704 ? f1 : 704;
  if (lo < hi) run_seg<true,true>(W8, lo, hi, 680, 112, 160, 96, 120, -1.f,
                                  in_lds, Bh, Bl, lane, e0, oa_g);
  // col9: w2r [704,712)
  lo = f0 > 704 ? f0 : 704; hi = f1 < 712 ? f1 : 712;
  if (lo < hi) run_seg<true,true>(W8, lo, hi, 704, 224, 208, 128, 136, 1.f,
                                  in_lds, Bh, Bl, lane, e0, oa_g);
  // col10: w2i [712,720)
  lo = f0 > 712 ? f0 : 712; hi = f1 < 720 ? f1 : 720;
  if (lo < hi) run_seg<true,true>(W8, lo, hi, 712, 208, 224, 128, 136, -1.f,
                                  in_lds, Bh, Bl, lane, e0, oa_g);
}

// -------------------------------------------- K4: per-edge epilogue (wave per edge)
__global__ __launch_bounds__(256)
void k4_epi(const float* __restrict__ oa_g, const float* __restrict__ Rm,
            const float* __restrict__ D2bm, const float* __restrict__ wenvg,
            const int* __restrict__ eidx, const int* __restrict__ act,
            const float* __restrict__ Wp0, const float* __restrict__ bp0,
            const float* __restrict__ Wp1, const float* __restrict__ Wp2,
            float* __restrict__ accg) {
  __shared__ float sc[4][160];    // gates 0..55 | y1g 56..103 | y2g 104..143
  const int wave = threadIdx.x >> 6, lane = threadIdx.x & 63;
  const int eg = blockIdx.x*4 + wave;
  const float* o_ = oa_g + (size_t)eg*144;
  if (lane < 56) {
    float v = o_[lane];
    sc[wave][lane] = (lane < 32) ? v/(1.f + expf(-v)) : 1.f/(1.f + expf(-v));
  }
  __syncthreads();
  const float* Rr = Rm + (size_t)eg*9;
  const float* Db = D2bm + (size_t)eg*25;
  if (lane < 48) {
    int u = lane/3, cc = lane - u*3;
    float yx = o_[104+u], yy = o_[56+u], yz = o_[80+u];
    float p = Rr[cc]*yx + Rr[3+cc]*yy + Rr[6+cc]*yz;
    sc[wave][56+lane] = p * sc[wave][32+u];
  }
  __syncthreads();
  if (lane < 40) {
    int u = lane/5, ii = lane - u*5;
    float y0 = o_[136+u], y1v = o_[120+u], y2v = o_[72+u], y3 = o_[96+u], y4 = o_[128+u];
    float p = Db[ii*5+0]*y0 + Db[ii*5+1]*y1v + Db[ii*5+2]*y2v + Db[ii*5+3]*y3 + Db[ii*5+4]*y4;
    sc[wave][104+lane] = p * sc[wave][48+u];
  }
  __syncthreads();
  const float* we = wenvg + (size_t)eg*56;
  const int ctr = eidx[act[eg]];
  float* dst = accg + (size_t)ctr*120;
#pragma unroll
  for (int rnd = 0; rnd < 2; ++rnd) {
    int jo = rnd*64 + lane;
    if (jo < 120) {
      float val;
      if (jo < 32) {
        float s = 0.f;
#pragma unroll
        for (int i2 = 0; i2 < 32; ++i2) s += sc[wave][i2]*Wp0[i2*32 + jo];
        val = (s*INV_SQRT32 + bp0[jo]) * we[jo];
      } else if (jo < 80) {
        int jj = jo-32, v = jj/3, cc = jj - v*3;
        float s = 0.f;
#pragma unroll
        for (int u = 0; u < 16; ++u) s += sc[wave][56 + u*3 + cc]*Wp1[u*16 + v];
        val = s*INV_SQRT16*we[32+v];
      } else {
        int jj = jo-80, v = jj/5, ii = jj - v*5;
        float s = 0.f;
#pragma unroll
        for (int u = 0; u < 8; ++u) s += sc[wave][104 + u*5 + ii]*Wp2[u*8 + v];
        val = s*INV_SQRT8*we[48+v];
      }
      atomicAdd(&dst[jo], val);
    }
  }
}

// -------------------------------------------- K5: residual path + combine
__global__ void k5_final(const float* __restrict__ x_all,
                         const float* __restrict__ Wr0, const float* __restrict__ br0,
                         const float* __restrict__ Wr1, const float* __restrict__ Wr2,
                         const float* __restrict__ accg,
                         float* __restrict__ out) {
  const int n = blockIdx.x;
  const int t = threadIdx.x;
  if (t >= 120) return;
  const float* x = x_all + n*120;
  float r;
  if (t < 32) {
    float s = 0.f;
#pragma unroll
    for (int i = 0; i < 32; ++i) s += x[i]*Wr0[i*32 + t];
    r = s*INV_SQRT32 + br0[t];
  } else if (t < 80) {
    int j = t - 32, v = j/3, cp = j - 3*v;
    float s = 0.f;
#pragma unroll
    for (int u = 0; u < 16; ++u) s += x[32 + u*3 + cp]*Wr1[u*16 + v];
    r = s*INV_SQRT16;
  } else {
    int j = t - 80, v = j/5, cp = j - 5*v;
    float s = 0.f;
#pragma unroll
    for (int u = 0; u < 8; ++u) s += x[80 + u*5 + cp]*Wr2[u*8 + v];
    r = s*INV_SQRT8;
  }
  out[n*120 + t] = C_NEW_*(NORMC*accg[n*120 + t]) + C_OLD_*r;
}

// ---------------------------------------------------------------- launcher
extern "C" void kernel_launch(void* const* d_in, const int* in_sizes, int n_in,
                              void* d_out, int out_size, void* d_ws, size_t ws_size,
                              hipStream_t stream) {
  const float* lat  = (const float*)d_in[0];
  const float* ndf  = (const float*)d_in[1];
  const float* hid  = (const float*)d_in[2];
  const float* evec = (const float*)d_in[4];
  const float* Wtp  = (const float*)d_in[5];
  const float* Wenv = (const float*)d_in[6];
  const float* w0   = (const float*)d_in[7];
  const float* b0   = (const float*)d_in[8];
  const float* w1   = (const float*)d_in[9];
  const float* w2   = (const float*)d_in[10];
  const float* Wp0  = (const float*)d_in[11];
  const float* bp0  = (const float*)d_in[12];
  const float* Wp1  = (const float*)d_in[13];
  const float* Wp2  = (const float*)d_in[14];
  const float* Wr0  = (const float*)d_in[15];
  const float* br0  = (const float*)d_in[16];
  const float* Wr1  = (const float*)d_in[17];
  const float* Wr2  = (const float*)d_in[18];
  const int*   eidx = (const int*)d_in[20];
  const int*   act  = (const int*)d_in[21];
  float* out = (float*)d_out;

  char* p = (char*)d_ws;
  float*    nf    = (float*)(p);                       // 512*120*4      = 245760
  float*    invT  = (float*)(p + 245760);              // 240*10240*4    = 9830400
  float*    Rm    = (float*)(p + 10076160);            // 10240*9*4      = 368640
  float*    D2bm  = (float*)(p + 10444800);            // 10240*25*4     = 1024000
  float*    wenv  = (float*)(p + 11468800);            // 10240*56*4     = 2293760
  float*    accg  = (float*)(p + 13762560);            // 512*120*4      = 245760
  float*    oa_g  = (float*)(p + 14008320);            // 10240*144*4    = 5898240
  ushort_t* lath  = (ushort_t*)(p + 19906560);         // 10240*128*2    = 2621440
  ushort_t* latl  = (ushort_t*)(p + 22528000);         // 2621440
  ushort_t* Wpack = (ushort_t*)(p + 25149440);         // 720*8*512*2    = 5898240 (end 31047680)

  hipMemsetAsync(accg, 0, 245760, stream);
  hipMemsetAsync(oa_g, 0, 5898240, stream);
  k0_latpack<<<(E_TOT*128 + 255)/256, 256, 0, stream>>>(lat, lath, latl);
  k_pack<<<720, 256, 0, stream>>>(Wtp, Wpack);
  k1_sln<<<N_NODES, 64, 0, stream>>>(ndf, w0, b0, w1, w2, nf);
  k2_edge_prep<<<E_TOT/256, 256, 0, stream>>>(hid, evec, eidx, act, nf, invT, Rm, D2bm);
  k2_wenv<<<E_TOT/4, 256, 0, stream>>>(lat, Wenv, act, wenv);
  k3_gemm<<<dim3(E_TOT/32, 4), 256, 0, stream>>>(Wpack, lath, latl, invT, oa_g);
  k4_epi<<<E_TOT/4, 256, 0, stream>>>(oa_g, Rm, D2bm, wenv, eidx, act, Wp0, bp0, Wp1, Wp2, accg);
  k5_final<<<N_NODES, 128, 0, stream>>>(ndf, Wr0, br0, Wr1, Wr2, accg, out);
}

// Round 4
// 301.293 us; speedup vs baseline: 1.1421x; 1.1421x over previous
//
#include <hip/hip_runtime.h>
#include <math.h>

#define E_TOT   10240
#define N_NODES 512
#define NCOL    11520

typedef unsigned short ushort_t;
typedef unsigned int   uint_t;
typedef __bf16 bf16x8 __attribute__((ext_vector_type(8)));
typedef float  f32x4  __attribute__((ext_vector_type(4)));

constexpr float EPSF        = 1e-5f;
constexpr float INV_SQRT128 = 0.08838834764831845f;
constexpr float INV_SQRT112 = 0.09449111825230681f;
constexpr float INV_SQRT48  = 0.14433756729740643f;
constexpr float INV_SQRT32  = 0.17677669529663687f;
constexpr float INV_SQRT16  = 0.25f;
constexpr float INV_SQRT8   = 0.35355339059327373f;
constexpr float SC0 = INV_SQRT128 * INV_SQRT112;
constexpr float SC1 = INV_SQRT128 * INV_SQRT48;
constexpr float SC2 = INV_SQRT128 * INV_SQRT16;
constexpr float C_OLD_ = 0.8944271909999159f;
constexpr float C_NEW_ = 0.4472135954999579f;
constexpr float NORMC  = 0.22360679774997896f;

// ---------------------------------------------------------------- utilities
__device__ __forceinline__ float wsum(float v) {
#pragma unroll
  for (int off = 32; off > 0; off >>= 1) v += __shfl_xor(v, off, 64);
  return v;
}

__device__ __forceinline__ ushort_t f2bf(float x) {
  uint_t u = __float_as_uint(x);
  u = (u + 0x7fffu + ((u >> 16) & 1u)) >> 16;
  return (ushort_t)u;
}

// Analytic Wigner-D (l=2) in basis {xy, yz, 3z^2-1, xz, x^2-y^2}.
__device__ __forceinline__ void wigner5(const float q[9], float D[25]) {
  const float q0x=q[0],q0y=q[1],q0z=q[2];
  const float q1x=q[3],q1y=q[4],q1z=q[5];
  const float q2x=q[6],q2y=q[7],q2z=q[8];
  D[0]  = q0x*q1y + q1x*q0y;
  D[1]  = q0y*q1z + q1y*q0z;
  D[2]  = 0.5f*(q0z*q1z);
  D[3]  = q0x*q1z + q1x*q0z;
  D[4]  = 0.5f*(q0x*q1x - q0y*q1y);
  D[5]  = q1x*q2y + q2x*q1y;
  D[6]  = q1y*q2z + q2y*q1z;
  D[7]  = 0.5f*(q1z*q2z);
  D[8]  = q1x*q2z + q2x*q1z;
  D[9]  = 0.5f*(q1x*q2x - q1y*q2y);
  D[10] = 6.f*q2x*q2y;
  D[11] = 6.f*q2y*q2z;
  D[12] = 0.5f*(3.f*q2z*q2z - 1.f);
  D[13] = 6.f*q2x*q2z;
  D[14] = 1.5f*(q2x*q2x - q2y*q2y);
  D[15] = q0x*q2y + q2x*q0y;
  D[16] = q0y*q2z + q2y*q0z;
  D[17] = 0.5f*(q0z*q2z);
  D[18] = q0x*q2z + q2x*q0z;
  D[19] = 0.5f*(q0x*q2x - q0y*q2y);
  D[20] = 2.f*(q0x*q0y - q1x*q1y);
  D[21] = 2.f*(q0y*q0z - q1y*q1z);
  D[22] = 0.5f*(q0z*q0z - q1z*q1z);
  D[23] = 2.f*(q0x*q0z - q1x*q1z);
  D[24] = 0.5f*((q0x*q0x - q1x*q1x) - (q0y*q0y - q1y*q1y));
}

// ---------------------------------------------------------------- K0: latents -> bf16 hi/lo
__global__ void k0_latpack(const float* __restrict__ lat,
                           ushort_t* __restrict__ lath, ushort_t* __restrict__ latl) {
  int idx = blockIdx.x*256 + threadIdx.x;
  if (idx >= E_TOT*128) return;
  float x = lat[idx];
  ushort_t h = f2bf(x);
  float hf = __uint_as_float(((uint_t)h) << 16);
  lath[idx] = h;
  latl[idx] = f2bf(x - hf);
}

// -------------------------------------- K_pack: W_tp -> contiguous-c MFMA fragments
// Column table (720 tiles):
//  col0-4 : sec0 o-block a=col, depth 112, c = t*80 + 16a + m
//  col5   : w1r oA, depth 48, c = 8960 + t*24 + m
//  col6   : w1r oB, depth 24, c = 8960 + (2t+(m>>3))*24 + 16 + (m&7)
//  col7   : w1i oA, depth 48;  col8: w1i oB, depth 24
//  col9   : w2r, depth 8;      col10: w2i, depth 8
// Fragment layout: frag(nt,kc,s)[lane][8] at ((nt*8 + kc*2 + s)*512 + lane*8)
__global__ void k_pack(const float* __restrict__ Wtp, ushort_t* __restrict__ Wp) {
  const int nt = blockIdx.x;
  const int t = threadIdx.x;
  const int kc = t >> 6, lane = t & 63;
  const int m = lane & 15, kg = lane >> 4;
  int col, tt;
  if (nt < 560)      { col = nt/112; tt = nt - col*112; }
  else if (nt < 608) { col = 5;  tt = nt-560; }
  else if (nt < 632) { col = 6;  tt = nt-608; }
  else if (nt < 680) { col = 7;  tt = nt-632; }
  else if (nt < 704) { col = 8;  tt = nt-680; }
  else if (nt < 712) { col = 9;  tt = nt-704; }
  else               { col = 10; tt = nt-712; }
  int c; float sc;
  switch (col) {
    case 5:  c = 8960  + tt*24 + m;                       sc = SC1; break;
    case 6:  c = 8960  + (2*tt + (m>>3))*24 + 16 + (m&7); sc = SC1; break;
    case 7:  c = 10112 + tt*24 + m;                       sc = SC1; break;
    case 8:  c = 10112 + (2*tt + (m>>3))*24 + 16 + (m&7); sc = SC1; break;
    case 9:  c = 11264 + (2*tt + (m>>3))*8 + (m&7);       sc = SC2; break;
    case 10: c = 11392 + (2*tt + (m>>3))*8 + (m&7);       sc = SC2; break;
    default: c = tt*80 + col*16 + m;                      sc = SC0; break;
  }
  ushort_t hi[8], lo[8];
#pragma unroll
  for (int jj = 0; jj < 8; ++jj) {
    int l = kc*32 + kg*8 + jj;
    float w = Wtp[(size_t)l*NCOL + c] * sc;
    ushort_t h = f2bf(w);
    float hf = __uint_as_float(((uint_t)h) << 16);
    hi[jj] = h;
    lo[jj] = f2bf(w - hf);
  }
  size_t base = ((size_t)nt*8 + kc*2)*512 + (size_t)lane*8;
#pragma unroll
  for (int jj = 0; jj < 8; ++jj) {
    Wp[base + jj]       = hi[jj];
    Wp[base + 512 + jj] = lo[jj];
  }
}

// ---------------------------------------------------------------- K1: _sln
__global__ void k1_sln(const float* __restrict__ x_all,
                       const float* __restrict__ w0, const float* __restrict__ b0,
                       const float* __restrict__ w1, const float* __restrict__ w2,
                       float* __restrict__ nf) {
  const int n = blockIdx.x;
  const int t = threadIdx.x;
  const float* x = x_all + n*120;
  float xs = (t < 32) ? x[t] : 0.f;
  float ssum = wsum(xs);
  float ssq  = wsum(xs*xs);
  float mu   = ssum * (1.f/32.f);
  float var  = ssq * (1.f/32.f) - mu*mu;
  float istd = rsqrtf(var + EPSF);
  float q1 = (t < 48) ? x[32+t] : 0.f;
  float v1s = wsum(q1*q1);
  float q2 = (t < 40) ? x[80+t] : 0.f;
  float v2s = wsum(q2*q2);
  float inv = rsqrtf(0.5f*(v1s*(1.f/48.f) + v2s*(1.f/40.f)) + EPSF);
  for (int j = t; j < 120; j += 64) {
    float val = x[j], r;
    if (j < 32)      r = (val - mu)*istd*w0[j] + b0[j];
    else if (j < 80) r = val*inv*w1[(j-32)/3];
    else             r = val*inv*w2[(j-80)/5];
    nf[n*120 + j] = r;
  }
}

// ------------------------------------------------- K2: per-edge preprocessing
// invT layout: [r][E_TOT]  (r = 0..239), coalesced stores across lanes.
// rows: in0 @0 (112) | inn1 @112 (48) | inp1 @160 (48) | inn2 @208 (16) | inp2 @224 (16)
__global__ void k2_edge_prep(const float* __restrict__ hid,
                             const float* __restrict__ evec,
                             const int*   __restrict__ eidx,
                             const int*   __restrict__ act,
                             const float* __restrict__ nf,
                             float* __restrict__ invT,
                             float* __restrict__ Rm,
                             float* __restrict__ D2bm) {
  const int e = blockIdx.x*blockDim.x + threadIdx.x;
  if (e >= E_TOT) return;
  const int ae  = act[e];
  const int ctr = eidx[ae];
  float vx = evec[ae*3+0], vy = evec[ae*3+1], vz = evec[ae*3+2];
  float rn = rsqrtf(vx*vx + vy*vy + vz*vz);
  float nx = vx*rn, ny = vy*rn, nz = vz*rn;
  float e1x, e1y, e1z;
  if (fabsf(nz) < 0.99f) { e1x = -ny; e1y = nx;  e1z = 0.f; }
  else                   { e1x = 0.f; e1y = -nz; e1z = ny;  }
  float rl = rsqrtf(e1x*e1x + e1y*e1y + e1z*e1z);
  e1x *= rl; e1y *= rl; e1z *= rl;
  float e2x = ny*e1z - nz*e1y;
  float e2y = nz*e1x - nx*e1z;
  float e2z = nx*e1y - ny*e1x;
  float R[9] = {e1x,e1y,e1z, e2x,e2y,e2z, nx,ny,nz};
#pragma unroll
  for (int j = 0; j < 9; ++j) Rm[e*9 + j] = R[j];
  float Df[25];
  wigner5(R, Df);
  float Rt[9] = {R[0],R[3],R[6], R[1],R[4],R[7], R[2],R[5],R[8]};
  float Db[25];
  wigner5(Rt, Db);
#pragma unroll
  for (int j = 0; j < 25; ++j) D2bm[e*25 + j] = Db[j];
  const float* xa = nf  + (size_t)ctr*120;
  const float* xb = hid + (size_t)e*120;
#define IVST(r_, v_) invT[(size_t)(r_)*E_TOT + e] = (v_)
#pragma unroll
  for (int j = 0; j < 32; ++j) { IVST(j, xa[j]); IVST(32+j, xb[j]); }
#pragma unroll
  for (int u = 0; u < 32; ++u) {
    const float* src = (u < 16) ? (xa + 32 + 3*u) : (xb + 32 + 3*(u-16));
    float px = src[0], py = src[1], pz = src[2];
    float rx = R[0]*px + R[1]*py + R[2]*pz;
    float ry = R[3]*px + R[4]*py + R[5]*pz;
    float rz = R[6]*px + R[7]*py + R[8]*pz;
    IVST(64+u, ry);
    IVST(112+u, rx);
    IVST(160+u, rz);
  }
#pragma unroll
  for (int u = 0; u < 16; ++u) {
    const float* src = (u < 8) ? (xa + 80 + 5*u) : (xb + 80 + 5*(u-8));
    float p0 = src[0], p1 = src[1], p2 = src[2], p3 = src[3], p4 = src[4];
    float d[5];
#pragma unroll
    for (int i = 0; i < 5; ++i)
      d[i] = Df[i*5+0]*p0 + Df[i*5+1]*p1 + Df[i*5+2]*p2 + Df[i*5+3]*p3 + Df[i*5+4]*p4;
    IVST(96+u,  d[2]);
    IVST(144+u, d[1]);
    IVST(192+u, d[3]);
    IVST(208+u, d[0]);
    IVST(224+u, d[4]);
  }
#undef IVST
}

// ------------------------------------------------- K2w: wenv, LDS-tiled
// Block = 256 threads = 256 edges; Wenv fully in LDS, lat staged in 16-l chunks.
__global__ __launch_bounds__(256)
void k2_wenv(const float* __restrict__ lat, const float* __restrict__ Wenv,
             const int* __restrict__ act, float* __restrict__ wenvo) {
  __shared__ float Wl[128*56];       // 28672 B
  __shared__ float latc[256*17];     // 17408 B (pad 17 vs 16)
  __shared__ int   aes[256];
  const int t = threadIdx.x;
  const int e0 = blockIdx.x*256;
  for (int i = t; i < 128*56; i += 256) Wl[i] = Wenv[i];
  aes[t] = act[e0 + t];
  float acc[56];
#pragma unroll
  for (int o = 0; o < 56; ++o) acc[o] = 0.f;
  for (int lc = 0; lc < 8; ++lc) {
    __syncthreads();
    for (int i = t; i < 256*16; i += 256) {
      int el = i >> 4, j = i & 15;
      latc[el*17 + j] = lat[(size_t)aes[el]*128 + lc*16 + j];
    }
    __syncthreads();
#pragma unroll
    for (int j = 0; j < 16; ++j) {
      float lv = latc[t*17 + j];
      const float* wr = &Wl[(lc*16 + j)*56];
#pragma unroll
      for (int o = 0; o < 56; ++o) acc[o] += lv * wr[o];
    }
  }
  float* dst = wenvo + (size_t)(e0 + t)*56;
#pragma unroll
  for (int o = 0; o < 56; ++o) dst[o] = acc[o] * INV_SQRT128;
}

// --------------------------- K3: MFMA GEMM; A staged in LDS shared by 4 waves
// Block: 256 thr = 4 waves x 32 edges = 128 edges. blockIdx.y in [0,9): 80 tiles.
// Chunks of 2 tiles (16 KB), double-buffered; prefetch via VGPR (load-early/store-late).
__global__ __launch_bounds__(256, 2)
void k3_gemm(const ushort_t* __restrict__ Wp,
             const ushort_t* __restrict__ lath,
             const ushort_t* __restrict__ latl,
             const float*  __restrict__ invT,
             float* __restrict__ oa_g) {
  __shared__ __align__(16) ushort_t abuf[2][8192];   // 2 x (2 tiles x 8 frags x 512)
  const int t = threadIdx.x;
  const int wave = t >> 6, lane = t & 63;
  const int le = lane & 15, g = lane >> 4, gh = g >> 1;
  const int fbase = blockIdx.y * 80;
  const int e0w = blockIdx.x*128 + wave*32;
  // ---- B fragments (wave's 32 edges)
  bf16x8 Bh[4][2], Bl[4][2];
#pragma unroll
  for (int kc = 0; kc < 4; ++kc)
#pragma unroll
    for (int n = 0; n < 2; ++n) {
      size_t off = (size_t)(e0w + n*16 + le)*128 + kc*32 + g*8;
      Bh[kc][n] = *(const bf16x8*)(lath + off);
      Bl[kc][n] = *(const bf16x8*)(latl + off);
    }
  // ---- segment state (wave-uniform scalars)
  int col, tt;
  if (fbase < 560)      { col = fbase/112; tt = fbase - col*112; }
  else if (fbase < 608) { col = 5;  tt = fbase-560; }
  else if (fbase < 632) { col = 6;  tt = fbase-608; }
  else if (fbase < 680) { col = 7;  tt = fbase-632; }
  else if (fbase < 704) { col = 8;  tt = fbase-680; }
  else if (fbase < 712) { col = 9;  tt = fbase-704; }
  else                  { col = 10; tt = fbase-712; }
  int mP_, mN_, sP_, sN_, segLen; float sg_; bool PAIR_, TWO_;
  auto setParams = [&](int cf) {
    if (cf < 5)       { segLen=112; mP_=0;   mN_=0;   sP_=cf*16; sN_=0;   sg_=1.f;  PAIR_=false; TWO_=false; }
    else if (cf == 5) { segLen=48;  mP_=160; mN_=112; sP_=80;  sN_=104; sg_=1.f;  PAIR_=false; TWO_=true; }
    else if (cf == 6) { segLen=24;  mP_=160; mN_=112; sP_=96;  sN_=120; sg_=1.f;  PAIR_=true;  TWO_=true; }
    else if (cf == 7) { segLen=48;  mP_=112; mN_=160; sP_=80;  sN_=104; sg_=-1.f; PAIR_=false; TWO_=true; }
    else if (cf == 8) { segLen=24;  mP_=112; mN_=160; sP_=96;  sN_=120; sg_=-1.f; PAIR_=true;  TWO_=true; }
    else if (cf == 9) { segLen=8;   mP_=224; mN_=208; sP_=128; sN_=136; sg_=1.f;  PAIR_=true;  TWO_=true; }
    else              { segLen=8;   mP_=208; mN_=224; sP_=128; sN_=136; sg_=-1.f; PAIR_=true;  TWO_=true; }
  };
  setParams(col);
  f32x4 aP0={0,0,0,0}, aP1={0,0,0,0}, aN0={0,0,0,0}, aN1={0,0,0,0};
  auto flush = [&]() {
#pragma unroll
    for (int r = 0; r < 4; ++r) {
      int mm = g*4 + r;
      int sp = sP_ + (PAIR_ ? (mm & 7) : mm);
      atomicAdd(&oa_g[(size_t)(e0w + le)*144 + sp], sg_*aP0[r]);
      atomicAdd(&oa_g[(size_t)(e0w + 16 + le)*144 + sp], sg_*aP1[r]);
      if (TWO_) {
        int sn = sN_ + (PAIR_ ? (mm & 7) : mm);
        atomicAdd(&oa_g[(size_t)(e0w + le)*144 + sn], aN0[r]);
        atomicAdd(&oa_g[(size_t)(e0w + 16 + le)*144 + sn], aN1[r]);
      }
    }
    aP0 = (f32x4){0,0,0,0}; aP1 = (f32x4){0,0,0,0};
    aN0 = (f32x4){0,0,0,0}; aN1 = (f32x4){0,0,0,0};
  };
  // ---- stage chunk 0
#pragma unroll
  for (int qq = 0; qq < 4; ++qq) {
    uint4 v = *(const uint4*)(Wp + ((size_t)fbase*8 + wave*4 + qq)*512 + lane*8);
    *(uint4*)&abuf[0][(wave*4 + qq)*512 + lane*8] = v;
  }
  __syncthreads();
  // ---- main loop: 40 chunks of 2 tiles
  for (int c = 0; c < 40; ++c) {
    const int cb = c & 1, nb = cb ^ 1;
    uint4 pre[4];
    const bool more = (c + 1) < 40;
    if (more) {
#pragma unroll
      for (int qq = 0; qq < 4; ++qq)
        pre[qq] = *(const uint4*)(Wp + ((size_t)(fbase + 2*(c+1))*8 + wave*4 + qq)*512 + lane*8);
    }
#pragma unroll
    for (int lt = 0; lt < 2; ++lt) {
      // multiplier gathers (prefetch before MFMAs)
      int idx = PAIR_ ? (2*tt + gh) : tt;
      int rowP = mP_ + idx;
      float mP0 = invT[(size_t)rowP*E_TOT + e0w + le];
      float mP1 = invT[(size_t)rowP*E_TOT + e0w + 16 + le];
      float mN0 = 0.f, mN1 = 0.f;
      if (TWO_) {
        int rowN = mN_ + idx;
        mN0 = invT[(size_t)rowN*E_TOT + e0w + le];
        mN1 = invT[(size_t)rowN*E_TOT + e0w + 16 + le];
      }
      f32x4 d0 = {0,0,0,0}, d1 = {0,0,0,0};
#pragma unroll
      for (int kc = 0; kc < 4; ++kc) {
        bf16x8 Ah = *(const bf16x8*)&abuf[cb][(lt*8 + kc*2 + 0)*512 + lane*8];
        bf16x8 Al = *(const bf16x8*)&abuf[cb][(lt*8 + kc*2 + 1)*512 + lane*8];
        d0 = __builtin_amdgcn_mfma_f32_16x16x32_bf16(Ah, Bh[kc][0], d0, 0, 0, 0);
        d1 = __builtin_amdgcn_mfma_f32_16x16x32_bf16(Ah, Bh[kc][1], d1, 0, 0, 0);
        d0 = __builtin_amdgcn_mfma_f32_16x16x32_bf16(Ah, Bl[kc][0], d0, 0, 0, 0);
        d1 = __builtin_amdgcn_mfma_f32_16x16x32_bf16(Ah, Bl[kc][1], d1, 0, 0, 0);
        d0 = __builtin_amdgcn_mfma_f32_16x16x32_bf16(Al, Bh[kc][0], d0, 0, 0, 0);
        d1 = __builtin_amdgcn_mfma_f32_16x16x32_bf16(Al, Bh[kc][1], d1, 0, 0, 0);
      }
#pragma unroll
      for (int r = 0; r < 4; ++r) { aP0[r] += mP0*d0[r]; aP1[r] += mP1*d1[r]; }
      if (TWO_) {
#pragma unroll
        for (int r = 0; r < 4; ++r) { aN0[r] += mN0*d0[r]; aN1[r] += mN1*d1[r]; }
      }
      tt++;
      if (tt == segLen) { flush(); col++; tt = 0; setParams(col); }
    }
    if (more) {
#pragma unroll
      for (int qq = 0; qq < 4; ++qq)
        *(uint4*)&abuf[nb][(wave*4 + qq)*512 + lane*8] = pre[qq];
    }
    __syncthreads();
  }
  if (tt > 0) flush();
}

// -------------------------------------------- K4: per-edge epilogue (wave per edge)
__global__ __launch_bounds__(256)
void k4_epi(const float* __restrict__ oa_g, const float* __restrict__ Rm,
            const float* __restrict__ D2bm, const float* __restrict__ wenvg,
            const int* __restrict__ eidx, const int* __restrict__ act,
            const float* __restrict__ Wp0, const float* __restrict__ bp0,
            const float* __restrict__ Wp1, const float* __restrict__ Wp2,
            float* __restrict__ accg) {
  __shared__ float sc[4][160];    // gates 0..55 | y1g 56..103 | y2g 104..143
  const int wave = threadIdx.x >> 6, lane = threadIdx.x & 63;
  const int eg = blockIdx.x*4 + wave;
  const float* o_ = oa_g + (size_t)eg*144;
  if (lane < 56) {
    float v = o_[lane];
    sc[wave][lane] = (lane < 32) ? v/(1.f + expf(-v)) : 1.f/(1.f + expf(-v));
  }
  __syncthreads();
  const float* Rr = Rm + (size_t)eg*9;
  const float* Db = D2bm + (size_t)eg*25;
  if (lane < 48) {
    int u = lane/3, cc = lane - u*3;
    float yx = o_[104+u], yy = o_[56+u], yz = o_[80+u];
    float p = Rr[cc]*yx + Rr[3+cc]*yy + Rr[6+cc]*yz;
    sc[wave][56+lane] = p * sc[wave][32+u];
  }
  __syncthreads();
  if (lane < 40) {
    int u = lane/5, ii = lane - u*5;
    float y0 = o_[136+u], y1v = o_[120+u], y2v = o_[72+u], y3 = o_[96+u], y4 = o_[128+u];
    float p = Db[ii*5+0]*y0 + Db[ii*5+1]*y1v + Db[ii*5+2]*y2v + Db[ii*5+3]*y3 + Db[ii*5+4]*y4;
    sc[wave][104+lane] = p * sc[wave][48+u];
  }
  __syncthreads();
  const float* we = wenvg + (size_t)eg*56;
  const int ctr = eidx[act[eg]];
  float* dst = accg + (size_t)ctr*120;
#pragma unroll
  for (int rnd = 0; rnd < 2; ++rnd) {
    int jo = rnd*64 + lane;
    if (jo < 120) {
      float val;
      if (jo < 32) {
        float s = 0.f;
#pragma unroll
        for (int i2 = 0; i2 < 32; ++i2) s += sc[wave][i2]*Wp0[i2*32 + jo];
        val = (s*INV_SQRT32 + bp0[jo]) * we[jo];
      } else if (jo < 80) {
        int jj = jo-32, v = jj/3, cc = jj - v*3;
        float s = 0.f;
#pragma unroll
        for (int u = 0; u < 16; ++u) s += sc[wave][56 + u*3 + cc]*Wp1[u*16 + v];
        val = s*INV_SQRT16*we[32+v];
      } else {
        int jj = jo-80, v = jj/5, ii = jj - v*5;
        float s = 0.f;
#pragma unroll
        for (int u = 0; u < 8; ++u) s += sc[wave][104 + u*5 + ii]*Wp2[u*8 + v];
        val = s*INV_SQRT8*we[48+v];
      }
      atomicAdd(&dst[jo], val);
    }
  }
}

// -------------------------------------------- K5: residual path + combine
__global__ void k5_final(const float* __restrict__ x_all,
                         const float* __restrict__ Wr0, const float* __restrict__ br0,
                         const float* __restrict__ Wr1, const float* __restrict__ Wr2,
                         const float* __restrict__ accg,
                         float* __restrict__ out) {
  const int n = blockIdx.x;
  const int t = threadIdx.x;
  if (t >= 120) return;
  const float* x = x_all + n*120;
  float r;
  if (t < 32) {
    float s = 0.f;
#pragma unroll
    for (int i = 0; i < 32; ++i) s += x[i]*Wr0[i*32 + t];
    r = s*INV_SQRT32 + br0[t];
  } else if (t < 80) {
    int j = t - 32, v = j/3, cp = j - 3*v;
    float s = 0.f;
#pragma unroll
    for (int u = 0; u < 16; ++u) s += x[32 + u*3 + cp]*Wr1[u*16 + v];
    r = s*INV_SQRT16;
  } else {
    int j = t - 80, v = j/5, cp = j - 5*v;
    float s = 0.f;
#pragma unroll
    for (int u = 0; u < 8; ++u) s += x[80 + u*5 + cp]*Wr2[u*8 + v];
    r = s*INV_SQRT8;
  }
  out[n*120 + t] = C_NEW_*(NORMC*accg[n*120 + t]) + C_OLD_*r;
}

// ---------------------------------------------------------------- launcher
extern "C" void kernel_launch(void* const* d_in, const int* in_sizes, int n_in,
                              void* d_out, int out_size, void* d_ws, size_t ws_size,
                              hipStream_t stream) {
  const float* lat  = (const float*)d_in[0];
  const float* ndf  = (const float*)d_in[1];
  const float* hid  = (const float*)d_in[2];
  const float* evec = (const float*)d_in[4];
  const float* Wtp  = (const float*)d_in[5];
  const float* Wenv = (const float*)d_in[6];
  const float* w0   = (const float*)d_in[7];
  const float* b0   = (const float*)d_in[8];
  const float* w1   = (const float*)d_in[9];
  const float* w2   = (const float*)d_in[10];
  const float* Wp0  = (const float*)d_in[11];
  const float* bp0  = (const float*)d_in[12];
  const float* Wp1  = (const float*)d_in[13];
  const float* Wp2  = (const float*)d_in[14];
  const float* Wr0  = (const float*)d_in[15];
  const float* br0  = (const float*)d_in[16];
  const float* Wr1  = (const float*)d_in[17];
  const float* Wr2  = (const float*)d_in[18];
  const int*   eidx = (const int*)d_in[20];
  const int*   act  = (const int*)d_in[21];
  float* out = (float*)d_out;

  char* p = (char*)d_ws;
  float*    nf    = (float*)(p);                       // 245760
  float*    invT  = (float*)(p + 245760);              // 9830400
  float*    Rm    = (float*)(p + 10076160);            // 368640
  float*    D2bm  = (float*)(p + 10444800);            // 1024000
  float*    wenv  = (float*)(p + 11468800);            // 2293760
  float*    accg  = (float*)(p + 13762560);            // 245760
  float*    oa_g  = (float*)(p + 14008320);            // 5898240
  ushort_t* lath  = (ushort_t*)(p + 19906560);         // 2621440
  ushort_t* latl  = (ushort_t*)(p + 22528000);         // 2621440
  ushort_t* Wpack = (ushort_t*)(p + 25149440);         // 5898240 (end 31047680)

  hipMemsetAsync(accg, 0, 245760, stream);
  hipMemsetAsync(oa_g, 0, 5898240, stream);
  k0_latpack<<<(E_TOT*128 + 255)/256, 256, 0, stream>>>(lat, lath, latl);
  k_pack<<<720, 256, 0, stream>>>(Wtp, Wpack);
  k1_sln<<<N_NODES, 64, 0, stream>>>(ndf, w0, b0, w1, w2, nf);
  k2_edge_prep<<<E_TOT/256, 256, 0, stream>>>(hid, evec, eidx, act, nf, invT, Rm, D2bm);
  k2_wenv<<<E_TOT/256, 256, 0, stream>>>(lat, Wenv, act, wenv);
  k3_gemm<<<dim3(E_TOT/128, 9), 256, 0, stream>>>(Wpack, lath, latl, invT, oa_g);
  k4_epi<<<E_TOT/4, 256, 0, stream>>>(oa_g, Rm, D2bm, wenv, eidx, act, Wp0, bp0, Wp1, Wp2, accg);
  k5_final<<<N_NODES, 128, 0, stream>>>(ndf, Wr0, br0, Wr1, Wr2, accg, out);
}